// Round 10
// baseline (754.428 us; speedup 1.0000x reference)
//
#include <hip/hip_runtime.h>
#include <cstdint>
#include <cstddef>

// GCN via associativity: relu((A@H)@W^T) == relu(A@(H@W^T)).
// Round-10 structure: S1 un-fused. Rounds 7-9 proved the fused
// convert+GEMM runs at 3.9 TB/s regardless of staging structure (granule,
// occupancy, async in-flight all refuted); pure streaming kernels (fills,
// m13 copy) hit 6.3-6.5 TB/s. So:
//   k_conv: pure copy-convert fp32 A -> frag-tiled bf16 Abf (m13 shape:
//           lean, grid-stride, nt loads, 1KB dense stores, no compute deps)
//   L1 GEMM: k_spmm1<ASRC=1> reads Abf tiles (the known-good S2 pattern, D=64)
//   S2/S3:   k_spmm2 unchanged (97us each, near ceiling)
// Abf tile layout [rowgrp][kblk][64 lanes][8 slots] with the k-slot perm
// matching PT's (written by k_proj): lane (srow,kg) slots = k {kg*4..+3,
// 16+kg*4..+3} within each 32-k block.

#define NN 16384
#define SK1 8
#define KC1 (NN / SK1)   // 2048
#define SK2 16
#define KC2 (NN / SK2)   // 1024
#define NKB (NN / 32)    // 512 k-blocks

typedef __attribute__((ext_vector_type(8))) short s16x8;
typedef __attribute__((ext_vector_type(4))) float fx4;

__device__ __forceinline__ unsigned short f2bf_rne(float f) {
    unsigned int x = __builtin_bit_cast(unsigned int, f);
    x += 0x7fffu + ((x >> 16) & 1u);
    return (unsigned short)(x >> 16);
}

__device__ __forceinline__ s16x8 pack_bf(fx4 a, fx4 b) {
    s16x8 t;
    t[0] = (short)f2bf_rne(a[0]);
    t[1] = (short)f2bf_rne(a[1]);
    t[2] = (short)f2bf_rne(a[2]);
    t[3] = (short)f2bf_rne(a[3]);
    t[4] = (short)f2bf_rne(b[0]);
    t[5] = (short)f2bf_rne(b[1]);
    t[6] = (short)f2bf_rne(b[2]);
    t[7] = (short)f2bf_rne(b[3]);
    return t;
}

// ---------------------------------------------------------------------------
// Pure copy-convert: A32 -> Abf frag tiles. Unit u = (rowgrp g, kblk):
// lane (srow,kg) loads fp32 k {kg*4..+3, 16+kg*4..+3} of row g*16+srow,
// stores one 16B frag. Wave handles 64 consecutive units (contiguous 64KB
// dst stream; 16-row x 8KB src stripe). 2048 blocks, lean -> high occupancy.
// ---------------------------------------------------------------------------
__global__ __launch_bounds__(256) void k_conv(
    const float* __restrict__ A32, unsigned short* __restrict__ Abf)
{
    const int lane = threadIdx.x & 63;
    const int wv   = threadIdx.x >> 6;
    const int srow = lane & 15, kg = lane >> 4;
    const long w = blockIdx.x * 4 + wv;          // wave id, 0..8191
    const long u0 = w * 64;
#pragma unroll 4
    for (int j = 0; j < 64; ++j) {
        const long u = u0 + j;
        const long g = u >> 9;                   // u / NKB
        const long kblk = u & (NKB - 1);
        const float* p = A32 + (g * 16 + srow) * (long)NN + kblk * 32 + kg * 4;
        fx4 a0 = __builtin_nontemporal_load((const fx4*)p);
        fx4 a1 = __builtin_nontemporal_load((const fx4*)(p + 16));
        *(s16x8*)(Abf + (u * 64 + lane) * 8) = pack_bf(a0, a1);
    }
}

// ---------------------------------------------------------------------------
// L1 GEMM: part[s] = A@P1 (D=64). 2 row-tiles/wave. grid (NN/128, SK1).
// ASRC=1: read Abf tiles (1KB-dense); ASRC=0: read fp32 A (fallback).
// ---------------------------------------------------------------------------
template <int ASRC>
__global__ __launch_bounds__(256, 4) void k_spmm1(
    const float* __restrict__ A32,
    const unsigned short* __restrict__ Abf,  // [NN/16][NKB][64][8] bf16 tiles
    const unsigned short* __restrict__ PT,   // [64][NN] bf16, slot-permuted
    float* __restrict__ part)                // [SK1][NN][64] f32
{
    const int lane = threadIdx.x & 63;
    const int wv   = threadIdx.x >> 6;
    const int srow = lane & 15;
    const int kg   = lane >> 4;
    const int s    = blockIdx.y;
    const long kbeg = (long)s * KC1;
    const int rowbase = blockIdx.x * 128 + wv * 32;
    const long r0 = rowbase + srow;
    const long r1 = rowbase + 16 + srow;
    const long g0 = rowbase >> 4, g1 = g0 + 1;

    fx4 acc0[4], acc1[4];
#pragma unroll
    for (int c = 0; c < 4; ++c) {
        acc0[c] = (fx4){0.f, 0.f, 0.f, 0.f};
        acc1[c] = (fx4){0.f, 0.f, 0.f, 0.f};
    }

#pragma unroll 2
    for (int i = 0; i < KC1 / 32; ++i) {
        const long ko = kbeg + (long)i * 32;
        const long kblk = ko >> 5;
        s16x8 af0, af1;
        if (ASRC) {
            af0 = *(const s16x8*)(Abf + ((g0 * NKB + kblk) * 64 + lane) * 8);
            af1 = *(const s16x8*)(Abf + ((g1 * NKB + kblk) * 64 + lane) * 8);
        } else {
            const float* p0 = A32 + r0 * (long)NN + ko + kg * 4;
            const float* p1 = A32 + r1 * (long)NN + ko + kg * 4;
            fx4 a00 = __builtin_nontemporal_load((const fx4*)p0);
            fx4 a01 = __builtin_nontemporal_load((const fx4*)(p0 + 16));
            fx4 a10 = __builtin_nontemporal_load((const fx4*)p1);
            fx4 a11 = __builtin_nontemporal_load((const fx4*)(p1 + 16));
            af0 = pack_bf(a00, a01);
            af1 = pack_bf(a10, a11);
        }
#pragma unroll
        for (int c = 0; c < 4; ++c) {
            s16x8 bf = *(const s16x8*)(PT + (long)(c * 16 + srow) * NN + ko + kg * 8);
            acc0[c] = __builtin_amdgcn_mfma_f32_16x16x32_bf16(af0, bf, acc0[c], 0, 0, 0);
            acc1[c] = __builtin_amdgcn_mfma_f32_16x16x32_bf16(af1, bf, acc1[c], 0, 0, 0);
        }
    }
    // C layout: col = lane&15, row = (lane>>4)*4 + reg
    float* pbase = part + (long)s * NN * 64;
#pragma unroll
    for (int c = 0; c < 4; ++c)
#pragma unroll
        for (int r = 0; r < 4; ++r) {
            pbase[(long)(rowbase + kg * 4 + r) * 64 + c * 16 + srow]      = acc0[c][r];
            pbase[(long)(rowbase + 16 + kg * 4 + r) * 64 + c * 16 + srow] = acc1[c][r];
        }
}

// ---------------------------------------------------------------------------
// S2/S3: part[s] = A@P (D=32). 4 row-tiles/wave, frag-tiled bf16 A.
// ---------------------------------------------------------------------------
template <int ABF>
__global__ __launch_bounds__(256, 4) void k_spmm2(
    const unsigned short* __restrict__ Abf,
    const float* __restrict__ A32,
    const unsigned short* __restrict__ PT,   // [32][NN]
    float* __restrict__ part)                // [SK2][NN][32]
{
    const int lane = threadIdx.x & 63;
    const int wv   = threadIdx.x >> 6;
    const int srow = lane & 15;
    const int kg   = lane >> 4;
    const int s    = blockIdx.y;
    const long kbeg = (long)s * KC2;
    const int rowbase = blockIdx.x * 256 + wv * 64;
    const long g0 = rowbase >> 4;

    fx4 acc[4][2];
#pragma unroll
    for (int t = 0; t < 4; ++t)
#pragma unroll
        for (int c = 0; c < 2; ++c) acc[t][c] = (fx4){0.f, 0.f, 0.f, 0.f};

#pragma unroll 2
    for (int i = 0; i < KC2 / 32; ++i) {
        const long ko = kbeg + (long)i * 32;
        const long kblk = ko >> 5;
        s16x8 af[4];
        if (ABF) {
#pragma unroll
            for (int t = 0; t < 4; ++t)
                af[t] = *(const s16x8*)(Abf + (((g0 + t) * NKB + kblk) * 64 + lane) * 8);
        } else {
#pragma unroll
            for (int t = 0; t < 4; ++t) {
                const float* p = A32 + (long)(rowbase + t * 16 + srow) * NN + ko + kg * 4;
                fx4 a0 = __builtin_nontemporal_load((const fx4*)p);
                fx4 a1 = __builtin_nontemporal_load((const fx4*)(p + 16));
                af[t] = pack_bf(a0, a1);
            }
        }
        s16x8 b0 = *(const s16x8*)(PT + (long)srow * NN + ko + kg * 8);
        s16x8 b1 = *(const s16x8*)(PT + (long)(16 + srow) * NN + ko + kg * 8);
#pragma unroll
        for (int t = 0; t < 4; ++t) {
            acc[t][0] = __builtin_amdgcn_mfma_f32_16x16x32_bf16(af[t], b0, acc[t][0], 0, 0, 0);
            acc[t][1] = __builtin_amdgcn_mfma_f32_16x16x32_bf16(af[t], b1, acc[t][1], 0, 0, 0);
        }
    }
    float* pbase = part + (long)s * NN * 32;
#pragma unroll
    for (int t = 0; t < 4; ++t)
#pragma unroll
        for (int c = 0; c < 2; ++c)
#pragma unroll
            for (int r = 0; r < 4; ++r)
                pbase[(long)(rowbase + t * 16 + kg * 4 + r) * 32 + c * 16 + srow] = acc[t][c][r];
}

// ---------------------------------------------------------------------------
// Projection: PT[c][perm(r)] = bf16( act(H[r,:]) @ W[c,:] )
// ---------------------------------------------------------------------------
template <int DIN, int DOUT, int NSUM, bool RELU>
__global__ __launch_bounds__(256) void k_proj(
    const float* __restrict__ src,     // [NSUM][NN][DIN]
    const float* __restrict__ W,       // [DOUT][DIN]
    unsigned short* __restrict__ PT)   // [DOUT][NN] slot-permuted
{
    __shared__ float Ws[DOUT * DIN];
    __shared__ float Hs[64][DIN + 1];
    const int tid = threadIdx.x;
    for (int i = tid; i < DOUT * DIN; i += 256) Ws[i] = W[i];
    const int rbase = blockIdx.x * 64;
    for (int i = tid; i < 64 * DIN; i += 256) {
        const int rl = i / DIN, k = i % DIN;
        float v = 0.f;
#pragma unroll
        for (int s2 = 0; s2 < NSUM; ++s2)
            v += src[(long)s2 * NN * DIN + (long)(rbase + rl) * DIN + k];
        Hs[rl][k] = RELU ? fmaxf(v, 0.f) : v;
    }
    __syncthreads();
    const int rl = tid & 63;
    const int c0 = tid >> 6;
    const int r  = rbase + rl;
    const int kk = r & 31;
    const int pidx = (r & ~31) + ((kk & 15) >> 2) * 8 + (kk & 3) + ((kk >> 4) << 2);
    for (int c = c0; c < DOUT; c += 4) {
        float accv = 0.f;
#pragma unroll
        for (int k = 0; k < DIN; ++k) accv += Hs[rl][k] * Ws[c * DIN + k];
        PT[(long)c * NN + pidx] = f2bf_rne(accv);
    }
}

// Final reduce: out[NN][32] = sum_s part[s]
__global__ __launch_bounds__(256) void k_red(
    const float* __restrict__ part, float* __restrict__ out)
{
    const int e = blockIdx.x * 256 + threadIdx.x;
    if (e >= NN * 32 / 4) return;
    fx4 v = (fx4){0.f, 0.f, 0.f, 0.f};
#pragma unroll
    for (int s = 0; s < SK2; ++s)
        v += *(const fx4*)(part + (long)s * NN * 32 + (long)e * 4);
    *(fx4*)(out + (long)e * 4) = v;
}

extern "C" void kernel_launch(void* const* d_in, const int* in_sizes, int n_in,
                              void* d_out, int out_size, void* d_ws, size_t ws_size,
                              hipStream_t stream) {
    const float* A  = (const float*)d_in[0];
    const float* X  = (const float*)d_in[1];
    const float* W1 = (const float*)d_in[2];
    const float* W2 = (const float*)d_in[3];
    const float* W3 = (const float*)d_in[4];
    float* out = (float*)d_out;

    char* ws = (char*)d_ws;
    const size_t part_b = (size_t)SK1 * NN * 64 * 4;   // 32 MiB (== SK2*NN*32*4)
    const size_t pt_b   = (size_t)64 * NN * 2;         //  2 MiB
    const size_t abf_b  = (size_t)NN * NN * 2;         // 512 MiB
    float*          part = (float*)ws;
    unsigned short* PT   = (unsigned short*)(ws + part_b);
    unsigned short* Abf  = (unsigned short*)(ws + part_b + pt_b);
    const bool save = ws_size >= part_b + pt_b + abf_b;

    dim3 b(256);
    dim3 gP(NN / 64);
    dim3 g1(NN / 128, SK1);
    dim3 g2(NN / 256, SK2);

    // Layer 1: proj1 + (conv -> Abf-GEMM) | fallback fused-fp32 GEMM
    k_proj<64, 64, 1, false><<<gP, b, 0, stream>>>(X, W1, PT);
    if (save) {
        k_conv<<<dim3(2048), b, 0, stream>>>(A, Abf);
        k_spmm1<1><<<g1, b, 0, stream>>>(A, Abf, PT, part);
    } else {
        k_spmm1<0><<<g1, b, 0, stream>>>(A, Abf, PT, part);
    }

    // Layer 2
    k_proj<64, 32, SK1, true><<<gP, b, 0, stream>>>(part, W2, PT);
    if (save) k_spmm2<1><<<g2, b, 0, stream>>>(Abf, A, PT, part);
    else      k_spmm2<0><<<g2, b, 0, stream>>>(Abf, A, PT, part);

    // Layer 3
    k_proj<32, 32, SK2, true><<<gP, b, 0, stream>>>(part, W3, PT);
    if (save) k_spmm2<1><<<g2, b, 0, stream>>>(Abf, A, PT, part);
    else      k_spmm2<0><<<g2, b, 0, stream>>>(Abf, A, PT, part);

    k_red<<<dim3(NN * 32 / 4 / 256), b, 0, stream>>>(part, out);
}

// Round 11
// 727.838 us; speedup vs baseline: 1.0365x; 1.0365x over previous
//
#include <hip/hip_runtime.h>
#include <cstdint>
#include <cstddef>

// GCN via associativity: relu((A@H)@W^T) == relu(A@(H@W^T)).
// Round-11: monotone-read conv. Round-10 proved the pure copy-convert ALSO
// caps at ~4.1 TB/s with 16 interleaved read streams/wave, while monotone
// kernels (fill 6.4, m13 copy 6.29) stream fine. New k_conv: 1024-thr blocks,
// wave w reads row g*16+w MONOTONICALLY (1 stream/wave, 1KB/instr, nt),
// stages 512-k chunks in XOR-swizzled dbuf LDS, and the 16 waves emit
// frag-tiles as dense 1KB stores (wave w -> kblk-local w per chunk).
//   L1 GEMM: k_spmm1<1> reads Abf tiles (round-10, S2 pattern at D=64)
//   S2/S3:   k_spmm2 unchanged; proj/red unchanged.
// Abf tile layout [rowgrp][kblk][64 lanes][8 slots], slot perm matching PT:
// lane (srow,kg) slots = k {kg*4..+3, 16+kg*4..+3} within each 32-k block.

#define NN 16384
#define SK1 8
#define KC1 (NN / SK1)   // 2048
#define SK2 16
#define KC2 (NN / SK2)   // 1024
#define NKB (NN / 32)    // 512 k-blocks
#define CVK 512          // conv: k per staged chunk
#define CVNC (NN / CVK)  // 32 chunks

typedef __attribute__((ext_vector_type(8))) short s16x8;
typedef __attribute__((ext_vector_type(4))) float fx4;

__device__ __forceinline__ unsigned short f2bf_rne(float f) {
    unsigned int x = __builtin_bit_cast(unsigned int, f);
    x += 0x7fffu + ((x >> 16) & 1u);
    return (unsigned short)(x >> 16);
}

__device__ __forceinline__ s16x8 pack_bf(fx4 a, fx4 b) {
    s16x8 t;
    t[0] = (short)f2bf_rne(a[0]);
    t[1] = (short)f2bf_rne(a[1]);
    t[2] = (short)f2bf_rne(a[2]);
    t[3] = (short)f2bf_rne(a[3]);
    t[4] = (short)f2bf_rne(b[0]);
    t[5] = (short)f2bf_rne(b[1]);
    t[6] = (short)f2bf_rne(b[2]);
    t[7] = (short)f2bf_rne(b[3]);
    return t;
}

// ---------------------------------------------------------------------------
// Monotone-read copy-convert: A32 -> Abf frag tiles.
// Block = 1024 thr (16 waves) owns rowgroup g. Wave w reads row g*16+w
// monotonically; LDS chunk [16 rows][512 k] fp32, word XOR-swizzled by
// ((row&7)<<2) within 32-word blocks; wave w emits kblk c*16+w (1KB dense).
// ---------------------------------------------------------------------------
__global__ __launch_bounds__(1024) void k_conv(
    const float* __restrict__ A32, unsigned short* __restrict__ Abf)
{
    __shared__ float Asm[2][16][CVK];      // 2 x 32 KB
    const int tid = threadIdx.x;
    const int w = tid >> 6, lane = tid & 63;
    const int srow = lane & 15, kg = lane >> 4;
    const long g = blockIdx.x;             // row group (16 rows)
    const float* arow = A32 + (g * 16 + w) * (long)NN;
    fx4 ld0, ld1;

    auto LOAD = [&](int c) {
        ld0 = __builtin_nontemporal_load((const fx4*)(arow + (long)c * CVK + lane * 4));
        ld1 = __builtin_nontemporal_load((const fx4*)(arow + (long)c * CVK + 256 + lane * 4));
    };
    auto LDSW = [&](int buf) {
        const int sw = (w & 7) << 2;
        *(fx4*)&Asm[buf][w][(lane * 4) ^ sw]       = ld0;
        *(fx4*)&Asm[buf][w][(256 + lane * 4) ^ sw] = ld1;
    };
    auto EMIT = [&](int buf, int c) {
        const int base = w * 32 + kg * 4;            // k-local of slot 0
        const int sw = (srow & 7) << 2;
        fx4 a0 = *(const fx4*)&Asm[buf][srow][base ^ sw];
        fx4 a1 = *(const fx4*)&Asm[buf][srow][(base + 16) ^ sw];
        *(s16x8*)(Abf + ((g * NKB + (long)(c * 16 + w)) * 64 + lane) * 8) = pack_bf(a0, a1);
    };

    LOAD(0);
    LDSW(0);
    __syncthreads();
    for (int c = 0; c < CVNC; ++c) {
        if (c + 1 < CVNC) LOAD(c + 1);       // monotone next chunk
        EMIT(c & 1, c);
        if (c + 1 < CVNC) LDSW((c + 1) & 1); // other buffer; one barrier/chunk
        __syncthreads();
    }
}

// ---------------------------------------------------------------------------
// L1 GEMM: part[s] = A@P1 (D=64). 2 row-tiles/wave. grid (NN/128, SK1).
// ASRC=1: read Abf tiles (1KB-dense); ASRC=0: read fp32 A (fallback).
// ---------------------------------------------------------------------------
template <int ASRC>
__global__ __launch_bounds__(256, 4) void k_spmm1(
    const float* __restrict__ A32,
    const unsigned short* __restrict__ Abf,  // [NN/16][NKB][64][8] bf16 tiles
    const unsigned short* __restrict__ PT,   // [64][NN] bf16, slot-permuted
    float* __restrict__ part)                // [SK1][NN][64] f32
{
    const int lane = threadIdx.x & 63;
    const int wv   = threadIdx.x >> 6;
    const int srow = lane & 15;
    const int kg   = lane >> 4;
    const int s    = blockIdx.y;
    const long kbeg = (long)s * KC1;
    const int rowbase = blockIdx.x * 128 + wv * 32;
    const long r0 = rowbase + srow;
    const long r1 = rowbase + 16 + srow;
    const long g0 = rowbase >> 4, g1 = g0 + 1;

    fx4 acc0[4], acc1[4];
#pragma unroll
    for (int c = 0; c < 4; ++c) {
        acc0[c] = (fx4){0.f, 0.f, 0.f, 0.f};
        acc1[c] = (fx4){0.f, 0.f, 0.f, 0.f};
    }

#pragma unroll 2
    for (int i = 0; i < KC1 / 32; ++i) {
        const long ko = kbeg + (long)i * 32;
        const long kblk = ko >> 5;
        s16x8 af0, af1;
        if (ASRC) {
            af0 = *(const s16x8*)(Abf + ((g0 * NKB + kblk) * 64 + lane) * 8);
            af1 = *(const s16x8*)(Abf + ((g1 * NKB + kblk) * 64 + lane) * 8);
        } else {
            const float* p0 = A32 + r0 * (long)NN + ko + kg * 4;
            const float* p1 = A32 + r1 * (long)NN + ko + kg * 4;
            fx4 a00 = __builtin_nontemporal_load((const fx4*)p0);
            fx4 a01 = __builtin_nontemporal_load((const fx4*)(p0 + 16));
            fx4 a10 = __builtin_nontemporal_load((const fx4*)p1);
            fx4 a11 = __builtin_nontemporal_load((const fx4*)(p1 + 16));
            af0 = pack_bf(a00, a01);
            af1 = pack_bf(a10, a11);
        }
#pragma unroll
        for (int c = 0; c < 4; ++c) {
            s16x8 bf = *(const s16x8*)(PT + (long)(c * 16 + srow) * NN + ko + kg * 8);
            acc0[c] = __builtin_amdgcn_mfma_f32_16x16x32_bf16(af0, bf, acc0[c], 0, 0, 0);
            acc1[c] = __builtin_amdgcn_mfma_f32_16x16x32_bf16(af1, bf, acc1[c], 0, 0, 0);
        }
    }
    // C layout: col = lane&15, row = (lane>>4)*4 + reg
    float* pbase = part + (long)s * NN * 64;
#pragma unroll
    for (int c = 0; c < 4; ++c)
#pragma unroll
        for (int r = 0; r < 4; ++r) {
            pbase[(long)(rowbase + kg * 4 + r) * 64 + c * 16 + srow]      = acc0[c][r];
            pbase[(long)(rowbase + 16 + kg * 4 + r) * 64 + c * 16 + srow] = acc1[c][r];
        }
}

// ---------------------------------------------------------------------------
// S2/S3: part[s] = A@P (D=32). 4 row-tiles/wave, frag-tiled bf16 A.
// ---------------------------------------------------------------------------
template <int ABF>
__global__ __launch_bounds__(256, 4) void k_spmm2(
    const unsigned short* __restrict__ Abf,
    const float* __restrict__ A32,
    const unsigned short* __restrict__ PT,   // [32][NN]
    float* __restrict__ part)                // [SK2][NN][32]
{
    const int lane = threadIdx.x & 63;
    const int wv   = threadIdx.x >> 6;
    const int srow = lane & 15;
    const int kg   = lane >> 4;
    const int s    = blockIdx.y;
    const long kbeg = (long)s * KC2;
    const int rowbase = blockIdx.x * 256 + wv * 64;
    const long g0 = rowbase >> 4;

    fx4 acc[4][2];
#pragma unroll
    for (int t = 0; t < 4; ++t)
#pragma unroll
        for (int c = 0; c < 2; ++c) acc[t][c] = (fx4){0.f, 0.f, 0.f, 0.f};

#pragma unroll 2
    for (int i = 0; i < KC2 / 32; ++i) {
        const long ko = kbeg + (long)i * 32;
        const long kblk = ko >> 5;
        s16x8 af[4];
        if (ABF) {
#pragma unroll
            for (int t = 0; t < 4; ++t)
                af[t] = *(const s16x8*)(Abf + (((g0 + t) * NKB + kblk) * 64 + lane) * 8);
        } else {
#pragma unroll
            for (int t = 0; t < 4; ++t) {
                const float* p = A32 + (long)(rowbase + t * 16 + srow) * NN + ko + kg * 4;
                fx4 a0 = __builtin_nontemporal_load((const fx4*)p);
                fx4 a1 = __builtin_nontemporal_load((const fx4*)(p + 16));
                af[t] = pack_bf(a0, a1);
            }
        }
        s16x8 b0 = *(const s16x8*)(PT + (long)srow * NN + ko + kg * 8);
        s16x8 b1 = *(const s16x8*)(PT + (long)(16 + srow) * NN + ko + kg * 8);
#pragma unroll
        for (int t = 0; t < 4; ++t) {
            acc[t][0] = __builtin_amdgcn_mfma_f32_16x16x32_bf16(af[t], b0, acc[t][0], 0, 0, 0);
            acc[t][1] = __builtin_amdgcn_mfma_f32_16x16x32_bf16(af[t], b1, acc[t][1], 0, 0, 0);
        }
    }
    float* pbase = part + (long)s * NN * 32;
#pragma unroll
    for (int t = 0; t < 4; ++t)
#pragma unroll
        for (int c = 0; c < 2; ++c)
#pragma unroll
            for (int r = 0; r < 4; ++r)
                pbase[(long)(rowbase + t * 16 + kg * 4 + r) * 32 + c * 16 + srow] = acc[t][c][r];
}

// ---------------------------------------------------------------------------
// Projection: PT[c][perm(r)] = bf16( act(H[r,:]) @ W[c,:] )
// ---------------------------------------------------------------------------
template <int DIN, int DOUT, int NSUM, bool RELU>
__global__ __launch_bounds__(256) void k_proj(
    const float* __restrict__ src,     // [NSUM][NN][DIN]
    const float* __restrict__ W,       // [DOUT][DIN]
    unsigned short* __restrict__ PT)   // [DOUT][NN] slot-permuted
{
    __shared__ float Ws[DOUT * DIN];
    __shared__ float Hs[64][DIN + 1];
    const int tid = threadIdx.x;
    for (int i = tid; i < DOUT * DIN; i += 256) Ws[i] = W[i];
    const int rbase = blockIdx.x * 64;
    for (int i = tid; i < 64 * DIN; i += 256) {
        const int rl = i / DIN, k = i % DIN;
        float v = 0.f;
#pragma unroll
        for (int s2 = 0; s2 < NSUM; ++s2)
            v += src[(long)s2 * NN * DIN + (long)(rbase + rl) * DIN + k];
        Hs[rl][k] = RELU ? fmaxf(v, 0.f) : v;
    }
    __syncthreads();
    const int rl = tid & 63;
    const int c0 = tid >> 6;
    const int r  = rbase + rl;
    const int kk = r & 31;
    const int pidx = (r & ~31) + ((kk & 15) >> 2) * 8 + (kk & 3) + ((kk >> 4) << 2);
    for (int c = c0; c < DOUT; c += 4) {
        float accv = 0.f;
#pragma unroll
        for (int k = 0; k < DIN; ++k) accv += Hs[rl][k] * Ws[c * DIN + k];
        PT[(long)c * NN + pidx] = f2bf_rne(accv);
    }
}

// Final reduce: out[NN][32] = sum_s part[s]
__global__ __launch_bounds__(256) void k_red(
    const float* __restrict__ part, float* __restrict__ out)
{
    const int e = blockIdx.x * 256 + threadIdx.x;
    if (e >= NN * 32 / 4) return;
    fx4 v = (fx4){0.f, 0.f, 0.f, 0.f};
#pragma unroll
    for (int s = 0; s < SK2; ++s)
        v += *(const fx4*)(part + (long)s * NN * 32 + (long)e * 4);
    *(fx4*)(out + (long)e * 4) = v;
}

extern "C" void kernel_launch(void* const* d_in, const int* in_sizes, int n_in,
                              void* d_out, int out_size, void* d_ws, size_t ws_size,
                              hipStream_t stream) {
    const float* A  = (const float*)d_in[0];
    const float* X  = (const float*)d_in[1];
    const float* W1 = (const float*)d_in[2];
    const float* W2 = (const float*)d_in[3];
    const float* W3 = (const float*)d_in[4];
    float* out = (float*)d_out;

    char* ws = (char*)d_ws;
    const size_t part_b = (size_t)SK1 * NN * 64 * 4;   // 32 MiB (== SK2*NN*32*4)
    const size_t pt_b   = (size_t)64 * NN * 2;         //  2 MiB
    const size_t abf_b  = (size_t)NN * NN * 2;         // 512 MiB
    float*          part = (float*)ws;
    unsigned short* PT   = (unsigned short*)(ws + part_b);
    unsigned short* Abf  = (unsigned short*)(ws + part_b + pt_b);
    const bool save = ws_size >= part_b + pt_b + abf_b;

    dim3 b(256);
    dim3 gP(NN / 64);
    dim3 g1(NN / 128, SK1);
    dim3 g2(NN / 256, SK2);

    // Layer 1: proj1 + (monotone conv -> Abf-GEMM) | fallback fused-fp32 GEMM
    k_proj<64, 64, 1, false><<<gP, b, 0, stream>>>(X, W1, PT);
    if (save) {
        k_conv<<<dim3(NN / 16), dim3(1024), 0, stream>>>(A, Abf);
        k_spmm1<1><<<g1, b, 0, stream>>>(A, Abf, PT, part);
    } else {
        k_spmm1<0><<<g1, b, 0, stream>>>(A, Abf, PT, part);
    }

    // Layer 2
    k_proj<64, 32, SK1, true><<<gP, b, 0, stream>>>(part, W2, PT);
    if (save) k_spmm2<1><<<g2, b, 0, stream>>>(Abf, A, PT, part);
    else      k_spmm2<0><<<g2, b, 0, stream>>>(Abf, A, PT, part);

    // Layer 3
    k_proj<32, 32, SK2, true><<<gP, b, 0, stream>>>(part, W3, PT);
    if (save) k_spmm2<1><<<g2, b, 0, stream>>>(Abf, A, PT, part);
    else      k_spmm2<0><<<g2, b, 0, stream>>>(Abf, A, PT, part);

    k_red<<<dim3(NN * 32 / 4 / 256), b, 0, stream>>>(part, out);
}